// Round 13
// baseline (351.403 us; speedup 1.0000x reference)
//
#include <hip/hip_runtime.h>
#include <stdint.h>

typedef unsigned short ushort_t;
typedef __bf16 bf16x8 __attribute__((ext_vector_type(8)));
typedef __bf16 bf16x2 __attribute__((ext_vector_type(2)));
typedef float f32x4 __attribute__((ext_vector_type(4)));

#define T_SEQ 4096
#define D_MODEL 896
#define CHUNKS_PER_BLOCK 4   // target chunks per attention block (balance quantum)
#define MAXSPLIT 8           // max splits per tile (t=63 -> 8)

// Attention LDS strides (u16 units, 8-multiples for ds_read_b128 alignment).
#define LSK 136   // 68 dwords/row
#define LSV 72    // 36 dwords/row; lane=key scatter spans all 32 banks

// Fano lines, residues sorted ascending per head
__constant__ int d_LINEMASK[7] = {0x07, 0x19, 0x61, 0x2A, 0x52, 0x4C, 0x34};
__constant__ int d_R[7][3] = {{0,1,2},{0,3,4},{0,5,6},{1,3,5},{1,4,6},{2,3,6},{2,4,5}};

__device__ inline unsigned f2bf(float f) {
    unsigned x = __float_as_uint(f);
    return (x + 0x7fffu + ((x >> 16) & 1u)) >> 16;   // RNE
}
__device__ inline float lo_f(unsigned x) { return __uint_as_float(x << 16); }
__device__ inline float hi_f(unsigned x) { return __uint_as_float(x & 0xFFFF0000u); }

// pack two f32 -> u32 of 2 bf16 via HW cvt (RNE; compiler emits v_cvt_pk_bf16_f32)
__device__ __forceinline__ unsigned pk_bf2(float lo, float hi) {
    union { bf16x2 h; unsigned u; } cv;
    cv.h = (bf16x2){(__bf16)lo, (__bf16)hi};
    return cv.u;
}
__device__ __forceinline__ ushort_t bf1(float f) {
    union { __bf16 h; ushort_t u; } cv;
    cv.h = (__bf16)f;
    return cv.u;
}

// ---------------------------------------------------------------------------
// Static balanced schedule (R11). Head-independent upper bound on the chunk
// count of tile t; split count S(t) = ceil(ntot_ub/CHUNKS_PER_BLOCK) so every
// attention block runs <= 4 chunks. Same formula on host (grid size) and
// device (tile lookup); all wave-uniform SALU.
// ---------------------------------------------------------------------------
__host__ __device__ inline int nsplit_of(int t) {
    int a = (192 * t + 189) / 7 + 3;        // >= any head's ncomp for this tile
    int nch_ub = (a + 63) >> 6;             // >= any head's nch
    return (nch_ub + 2 + CHUNKS_PER_BLOCK - 1) / CHUNKS_PER_BLOCK;  // ntot_ub/4
}

// ---------------------------------------------------------------------------
// fp32 -> bf16 bulk convert, 5 tensors (x, Wq, Wk, Wv, Wo). 8 elem/thread.
// ---------------------------------------------------------------------------
__global__ __launch_bounds__(256)
void cvt5(const float* __restrict__ x,  const float* __restrict__ wq,
          const float* __restrict__ wk, const float* __restrict__ wv,
          const float* __restrict__ wo,
          ushort_t* __restrict__ xb,  ushort_t* __restrict__ wqb,
          ushort_t* __restrict__ wkb, ushort_t* __restrict__ wvb,
          ushort_t* __restrict__ wob) {
    const int ten = blockIdx.y;
    const float* s = (ten == 0) ? x : (ten == 1) ? wq : (ten == 2) ? wk
                   : (ten == 3) ? wv : wo;
    ushort_t* d = (ten == 0) ? xb : (ten == 1) ? wqb : (ten == 2) ? wkb
                : (ten == 3) ? wvb : wob;
    const int n8 = ((ten == 0) ? T_SEQ * D_MODEL : D_MODEL * D_MODEL) >> 3;
    for (int i = blockIdx.x * 256 + threadIdx.x; i < n8; i += gridDim.x * 256) {
        float4 a = ((const float4*)s)[2 * i];
        float4 b = ((const float4*)s)[2 * i + 1];
        uint4 u;
        u.x = f2bf(a.x) | (f2bf(a.y) << 16);
        u.y = f2bf(a.z) | (f2bf(a.w) << 16);
        u.z = f2bf(b.x) | (f2bf(b.y) << 16);
        u.w = f2bf(b.z) | (f2bf(b.w) << 16);
        ((uint4*)d)[i] = u;
    }
}

// async global->LDS DMA, 16 B/lane. LDS dest = wave-uniform base + lane*16.
__device__ __forceinline__ void async_cp16(const void* g, void* l) {
    __builtin_amdgcn_global_load_lds(
        (__attribute__((address_space(1))) void*)g,
        (__attribute__((address_space(3))) void*)l,
        16, 0, 0);
}

// ---------------------------------------------------------------------------
// C[M,N] = A[M,K] @ B[N,K]^T, bf16 in, fp32 acc, bf16/fp32 out (R9-verified).
// m97 structure: 128x128 tile, BK=32, DMA staging. z selects (B,C) pair.
// ---------------------------------------------------------------------------
template <bool C32>
__global__ __launch_bounds__(256)
void gemm_nt_dma(const ushort_t* __restrict__ A,
                 const ushort_t* __restrict__ B0,
                 const ushort_t* __restrict__ B1,
                 const ushort_t* __restrict__ B2,
                 void* __restrict__ C0,
                 void* __restrict__ C1,
                 void* __restrict__ C2) {
    const int z = blockIdx.z;
    const ushort_t* B = (z == 0) ? B0 : (z == 1) ? B1 : B2;
    void* C = (z == 0) ? C0 : (z == 1) ? C1 : C2;

    const int K = D_MODEL, N = D_MODEL;
    const int i0 = blockIdx.x * 128;
    const int n0 = blockIdx.y * 128;

    __shared__ __align__(16) ushort_t As[128 * 32];   // NO padding (DMA layout)
    __shared__ __align__(16) ushort_t Bs[128 * 32];

    const int t = threadIdx.x;
    const int w = t >> 6, lane = t & 63;
    const int wm = (w >> 1) * 64, wn = (w & 1) * 64;
    const int lr = lane & 15, lq = lane >> 4;

    const int srow = w * 16 + (lane >> 2);
    const int scol = (lane & 3) * 8;
    const ushort_t* gA0 = A + (size_t)(i0 + srow) * K + scol;
    const ushort_t* gA1 = A + (size_t)(i0 + 64 + srow) * K + scol;
    const ushort_t* gB0 = B + (size_t)(n0 + srow) * K + scol;
    const ushort_t* gB1 = B + (size_t)(n0 + 64 + srow) * K + scol;
    ushort_t* lA0 = &As[(w * 16) * 32];
    ushort_t* lA1 = &As[(64 + w * 16) * 32];
    ushort_t* lB0 = &Bs[(w * 16) * 32];
    ushort_t* lB1 = &Bs[(64 + w * 16) * 32];

    f32x4 acc[4][4];
#pragma unroll
    for (int a = 0; a < 4; a++)
#pragma unroll
        for (int b = 0; b < 4; b++) acc[a][b] = (f32x4){0.f, 0.f, 0.f, 0.f};

    for (int k0 = 0; k0 < K; k0 += 32) {
        __syncthreads();
        async_cp16(gA0 + k0, lA0);
        async_cp16(gA1 + k0, lA1);
        async_cp16(gB0 + k0, lB0);
        async_cp16(gB1 + k0, lB1);
        __builtin_amdgcn_s_waitcnt(0);
        __syncthreads();

        bf16x8 af[4], bfr[4];
#pragma unroll
        for (int mi = 0; mi < 4; mi++)
            af[mi] = *(const bf16x8*)&As[(wm + mi * 16 + lr) * 32 + lq * 8];
#pragma unroll
        for (int ni = 0; ni < 4; ni++)
            bfr[ni] = *(const bf16x8*)&Bs[(wn + ni * 16 + lr) * 32 + lq * 8];
#pragma unroll
        for (int mi = 0; mi < 4; mi++)
#pragma unroll
            for (int ni = 0; ni < 4; ni++)
                acc[mi][ni] = __builtin_amdgcn_mfma_f32_16x16x32_bf16(
                    af[mi], bfr[ni], acc[mi][ni], 0, 0, 0);
    }

    // C/D layout: col = lane&15, row = (lane>>4)*4 + reg
    if (C32) {
        float* Cf = (float*)C;
#pragma unroll
        for (int mi = 0; mi < 4; mi++)
#pragma unroll
            for (int ni = 0; ni < 4; ni++)
#pragma unroll
                for (int r = 0; r < 4; r++) {
                    int row = i0 + wm + mi * 16 + lq * 4 + r;
                    int col = n0 + wn + ni * 16 + lr;
                    Cf[(size_t)row * N + col] = acc[mi][ni][r];
                }
    } else {
        ushort_t* Cb = (ushort_t*)C;
#pragma unroll
        for (int mi = 0; mi < 4; mi++)
#pragma unroll
            for (int ni = 0; ni < 4; ni++)
#pragma unroll
                for (int r = 0; r < 4; r++) {
                    int row = i0 + wm + mi * 16 + lq * 4 + r;
                    int col = n0 + wn + ni * 16 + lr;
                    Cb[(size_t)row * N + col] = (ushort_t)f2bf(acc[mi][ni][r]);
                }
    }
}

// scatter 8 dims of one key's V into Vt[d][key] (stride LSV); lane=key mapping
__device__ inline void vt_scatter8(ushort_t* vtcol, uint4 vv) {
    vtcol[0 * LSV] = (ushort_t)(vv.x & 0xFFFFu);
    vtcol[1 * LSV] = (ushort_t)(vv.x >> 16);
    vtcol[2 * LSV] = (ushort_t)(vv.y & 0xFFFFu);
    vtcol[3 * LSV] = (ushort_t)(vv.y >> 16);
    vtcol[4 * LSV] = (ushort_t)(vv.z & 0xFFFFu);
    vtcol[5 * LSV] = (ushort_t)(vv.z >> 16);
    vtcol[6 * LSV] = (ushort_t)(vv.w & 0xFFFFu);
    vtcol[7 * LSV] = (ushort_t)(vv.w >> 16);
}

// compacted-index -> key: p -> j = 7*(p/3) + r[p%3]
__device__ inline int jof(int p, int r0, int r1, int r2) {
    int g = p / 3, rs = p - 3 * g;
    return 7 * g + ((rs == 0) ? r0 : (rs == 1) ? r1 : r2);
}

// issue chunk's K global loads into registers (16 VGPR; R21 K-only prefetch).
__device__ __forceinline__ void issue_k(const ushort_t* __restrict__ Kb,
                                        int j, int h, int dim0,
                                        uint4 kreg[4]) {
    if (j >= 0 && j < T_SEQ) {
        const ushort_t* kp = Kb + (size_t)j * D_MODEL + h * 128 + dim0;
#pragma unroll
        for (int v = 0; v < 4; v++) kreg[v] = *(const uint4*)(kp + v * 8);
    } else {
        uint4 zz = {0u, 0u, 0u, 0u};
#pragma unroll
        for (int v = 0; v < 4; v++) kreg[v] = zz;
    }
}

// stage: write prefetched K regs to Ks; load+scatter V directly (16 temp
// regs reused). V loads issue first (independent of kreg writes) so their
// latency overlaps the K LDS writes.
__device__ __forceinline__ void stage_kv(const ushort_t* __restrict__ Vb,
                                         ushort_t* Ks, ushort_t* Vt,
                                         int j, int kk, int dim0, int h,
                                         const uint4 kreg[4]) {
    if (j >= 0 && j < T_SEQ) {
        const ushort_t* vp = Vb + (size_t)j * D_MODEL + h * 128 + dim0;
        uint4 vv0 = *(const uint4*)(vp + 0);
        uint4 vv1 = *(const uint4*)(vp + 8);
        uint4 vv2 = *(const uint4*)(vp + 16);
        uint4 vv3 = *(const uint4*)(vp + 24);
#pragma unroll
        for (int v = 0; v < 4; v++)
            *(uint4*)&Ks[kk * LSK + dim0 + v * 8] = kreg[v];
        vt_scatter8(&Vt[(dim0 + 0) * LSV + kk], vv0);
        vt_scatter8(&Vt[(dim0 + 8) * LSV + kk], vv1);
        vt_scatter8(&Vt[(dim0 + 16) * LSV + kk], vv2);
        vt_scatter8(&Vt[(dim0 + 24) * LSV + kk], vv3);
    } else {
        uint4 zz = {0u, 0u, 0u, 0u};
#pragma unroll
        for (int v = 0; v < 4; v++) {
            *(uint4*)&Ks[kk * LSK + dim0 + v * 8] = zz;
            vt_scatter8(&Vt[(dim0 + v * 8) * LSV + kk], zz);
        }
    }
}

// ---------------------------------------------------------------------------
// Balanced split-K MFMA Fano attention (R21 = R20 + K-only reg prefetch).
// Grid (NP, 7), NP = sum_t nsplit_of(t); every block runs <= 4 chunks.
//
// R20 A/B result: no-prefetch@4blk (57.9us) beat prefetch@3blk (62.2us) —
// occupancy wins. R20 left 64 free regs at (256,4)'s 128 budget; R21
// spends 16 on prefetching K only (kreg), hiding the K half of the chunk
// gather across the compute section while keeping 4 blocks/CU. V stays
// direct-staged (its loads issue at the top of staging, partially covered
// by the kreg LDS writes). Live ~80 <= 128 — not the R12 spill regime.
//
// Structure (R12-R14, verified): S^T = mfma(A=K, B=Q); lane (lr,quad)
// holds S[q-row=lr][key=tn*16+quad*4+r]; in-lane softmax; in-register
// P->A-frag shuffle; no Ps LDS; interior fast-path; HW bf16 cvt; THR=8
// defer-max.
// ---------------------------------------------------------------------------
__global__ __launch_bounds__(256, 4)
void fano_attn_split(const ushort_t* __restrict__ Qb,
                     const ushort_t* __restrict__ Kb,
                     const ushort_t* __restrict__ Vb,
                     ushort_t* __restrict__ Opart,
                     float* __restrict__ Lm) {
    const int h = blockIdx.y;
    const int p = (int)gridDim.x - 1 - (int)blockIdx.x;  // LPT: big tiles first

    // tile lookup: find t with P[t] <= p < P[t]+S(t)  (wave-uniform)
    int tile = 63, pbase0 = 0;
    for (int u = 0; u < 64; ++u) {
        int s = nsplit_of(u);
        if (p < pbase0 + s) { tile = u; break; }
        pbase0 += s;
    }
    const int sp = p - pbase0;            // split index within tile
    const int Sloc = nsplit_of(tile);

    const int i0 = tile * 64;
    const int t = threadIdx.x;
    const int w = t >> 6, lane = t & 63;
    const int lr = lane & 15, quad = lane >> 4;
    const int iw0 = i0 + w * 16;

    __shared__ __align__(16) ushort_t Ks[64 * LSK];   // 17408 B
    __shared__ __align__(16) ushort_t Vt[128 * LSV];  // 18432 B

    const int lm = d_LINEMASK[h];
    const int r0 = d_R[h][0], r1 = d_R[h][1], r2 = d_R[h][2];
    const float scale = 0.08838834764831845f;

    // Q B-frags: lane holds Q[iw0+lr][f*32 + quad*8 + (0..7)]
    bf16x8 qf[4];
    {
        const ushort_t* qrow = Qb + (size_t)(iw0 + lr) * D_MODEL + h * 128;
#pragma unroll
        for (int f = 0; f < 4; f++)
            qf[f] = *(const bf16x8*)(qrow + f * 32 + quad * 8);
    }

    f32x4 O[8];
#pragma unroll
    for (int dt = 0; dt < 8; dt++) O[dt] = (f32x4){0.f, 0.f, 0.f, 0.f};
    float m = -1e30f;   // running max of q-row (iw0 + lr)
    float l = 0.f;      // running sum of q-row (iw0 + lr)

    const int imax = i0 + 63;
    const int ncomp = (imax - r0) / 7 + (imax - r1) / 7 + (imax - r2) / 7 + 3;
    const int nch = (ncomp + 63) >> 6;
    const int ntot = nch + 2;                // + two linear band chunks
    const int cstart = (sp * ntot) / Sloc;   // this split's chunk sub-range
    const int cend = ((sp + 1) * ntot) / Sloc;

    // per-lane key index for chunk cc (staging gather; lane = key slot)
    auto chunk_j = [&](int cc) -> int {
        if (cc >= nch) {
            const int jbase = (cc == nch) ? i0 - 16 : i0 + 48;
            return jbase + lane;
        }
        return jof(cc * 64 + lane, r0, r1, r2);
    };

    uint4 kreg[4];
    if (cstart < cend)
        issue_k(Kb, chunk_j(cstart), h, w * 32, kreg);

    const int iq = iw0 + lr;   // this lane's q-row

    for (int cc = cstart; cc < cend; cc++) {
        const bool band = (cc >= nch);
        const int jbase = (cc == nch) ? i0 - 16 : i0 + 48;

        __syncthreads();   // #1: prev chunk's LDS reads complete
        stage_kv(Vb, Ks, Vt, chunk_j(cc), lane, w * 32, h, kreg);
        __syncthreads();   // #2: staging visible to all waves

        // issue NEXT chunk's K loads now — in flight across the compute below
        if (cc + 1 < cend)
            issue_k(Kb, chunk_j(cc + 1), h, w * 32, kreg);

        // wave-uniform skip: chunk min j beyond this wave's rows
        {
            int jmin = band ? jbase : jof(cc * 64, r0, r1, r2);
            if (jmin > iw0 + 15) continue;
        }

        // S^T = K Q^T over 4 tiles of 16 keys (swapped operands)
        f32x4 S[4];
#pragma unroll
        for (int tn = 0; tn < 4; tn++) S[tn] = (f32x4){0.f, 0.f, 0.f, 0.f};
#pragma unroll
        for (int f = 0; f < 4; f++) {
            bf16x8 kf[4];
#pragma unroll
            for (int tn = 0; tn < 4; tn++)
                kf[tn] = *(const bf16x8*)&Ks[(tn * 16 + lr) * LSK + f * 32 + quad * 8];
#pragma unroll
            for (int tn = 0; tn < 4; tn++)
                S[tn] = __builtin_amdgcn_mfma_f32_16x16x32_bf16(kf[tn], qf[f], S[tn], 0, 0, 0);
        }

        // mask: lane holds S[q=iq][key = tn*16 + quad*4 + r].
        // Fast path (wave-uniform): interior fano chunk — every key <=
        // every row of this wave, keys are line-members by construction.
        const bool interior = !band && (jof(cc * 64 + 63, r0, r1, r2) <= iw0);
        if (interior) {
#pragma unroll
            for (int tn = 0; tn < 4; tn++)
#pragma unroll
                for (int r = 0; r < 4; r++) S[tn][r] *= scale;
        } else if (band) {
            // band: 0<=j<=i, j>=i-16, j%7 not in line (disjoint from fano)
#pragma unroll
            for (int tn = 0; tn < 4; tn++)
#pragma unroll
                for (int r = 0; r < 4; r++) {
                    int j = jbase + tn * 16 + quad * 4 + r;
                    int jm = ((j % 7) + 7) % 7;
                    bool ok = (j >= 0) && !((lm >> jm) & 1) &&
                              (j <= iq) && (j >= iq - 16);
                    S[tn][r] = ok ? S[tn][r] * scale : -1e30f;
                }
        } else {
            // straddling fano chunk: causal mask only
#pragma unroll
            for (int tn = 0; tn < 4; tn++) {
                int p0 = cc * 64 + tn * 16 + quad * 4;
                int g = p0 / 3, rs = p0 - 3 * g;
#pragma unroll
                for (int r = 0; r < 4; r++) {
                    int j = 7 * g + ((rs == 0) ? r0 : (rs == 1) ? r1 : r2);
                    S[tn][r] = (j <= iq) ? S[tn][r] * scale : -1e30f;
                    if (++rs == 3) { rs = 0; ++g; }
                }
            }
        }

        // online softmax: row = lr (lane-local 16 values + cross-quad reduce)
        float cm = -1e30f;
#pragma unroll
        for (int tn = 0; tn < 4; tn++)
#pragma unroll
            for (int r = 0; r < 4; r++) cm = fmaxf(cm, S[tn][r]);
        cm = fmaxf(cm, __shfl_xor(cm, 16));
        cm = fmaxf(cm, __shfl_xor(cm, 32));

        // T13 defer-max, THR=8: skip rescale when max growth <= 8 for all
        // rows in the wave; P bounded by e^8, bf16/f32-safe. The m >= -60
        // guard keeps all-masked rows on the exact path.
        const bool defer = __all(cm <= m + 8.f && m >= -60.f);
        float mn, a = 1.f;
        if (defer) {
            mn = m;
        } else {
            mn = fmaxf(fmaxf(m, cm), -60.f);   // all-masked -> exact 0
            a = __expf(m - mn);
            m = mn;
        }
        float pr[4][4];
        float rs_ = 0.f;
#pragma unroll
        for (int tn = 0; tn < 4; tn++)
#pragma unroll
            for (int r = 0; r < 4; r++) {
                pr[tn][r] = __expf(S[tn][r] - mn);
                rs_ += pr[tn][r];
            }
        rs_ += __shfl_xor(rs_, 16);
        rs_ += __shfl_xor(rs_, 32);
        if (defer) {
            l = l + rs_;
        } else {
            l = l * a + rs_;
            // O-rescale: O rows are quad*4+r; row's a from lane (quad*4+r)
            float a4[4];
#pragma unroll
            for (int r = 0; r < 4; r++) a4[r] = __shfl(a, quad * 4 + r);
#pragma unroll
            for (int dt = 0; dt < 8; dt++)
#pragma unroll
                for (int r = 0; r < 4; r++) O[dt][r] *= a4[r];
        }

        // P -> PV A-frag, in-register (16 shfl + 8 selects; no LDS).
        // lane (lr,quad) holds P[lr][tn*16+quad*4+r]; target needs
        // P[lr][quad*8..+7] (pf0) and P[lr][32+quad*8..+7] (pf1), which live
        // in lanes srcA=32*(quad&1)+lr (r=0..3) and srcB=srcA+16 (r=0..3).
        unsigned u01[4], u23[4];
#pragma unroll
        for (int tn = 0; tn < 4; tn++) {
            u01[tn] = pk_bf2(pr[tn][0], pr[tn][1]);
            u23[tn] = pk_bf2(pr[tn][2], pr[tn][3]);
        }
        const int srcA = 32 * (quad & 1) + lr;
        const int srcB = srcA + 16;
        const bool hi = (quad >= 2);
        uint4 t0, t1;
        {
            unsigned d0a = __shfl(u01[0], srcA), d0b = __shfl(u01[1], srcA);
            unsigned d1a = __shfl(u23[0], srcA), d1b = __shfl(u23[1], srcA);
            unsigned d2a = __shfl(u01[0], srcB), d2b = __shfl(u01[1], srcB);
            unsigned d3a = __shfl(u23[0], srcB), d3b = __shfl(u23[1], srcB);
            t0.x = hi ? d0b : d0a;
            t0.y = hi ? d1b : d1a;
            t0.z = hi ? d2b : d2a;
            t0.w = hi ? d3b : d3a;
        }
        {
            unsigned d0a = __shfl(u01[2], srcA), d0b = __shfl(u01[3], srcA);
            unsigned d1a = __shfl(u23[2], srcA), d1b = __shfl(u23[3], srcA);
            unsigned d2a = __shfl(u01[2], srcB), d2b = __shfl(u01[3], srcB);
            unsigned d3a = __shfl(u23[2], srcB), d3b = __shfl(u23[3], srcB);
            t1.x = hi ? d0b : d0a;
            t1.y = hi ? d1b : d1a;
            t1.z = hi ? d2b : d2a;
            t1.w = hi ? d3b : d3a;
        }
        bf16x8 pf0 = *(const bf16x8*)&t0;
        bf16x8 pf1 = *(const bf16x8*)&t1;

#pragma unroll
        for (int dt = 0; dt < 8; dt++) {
            bf16x8 v0 = *(const bf16x8*)&Vt[(dt * 16 + lr) * LSV + quad * 8];
            bf16x8 v1 = *(const bf16x8*)&Vt[(dt * 16 + lr) * LSV + 32 + quad * 8];
            O[dt] = __builtin_amdgcn_mfma_f32_16x16x32_bf16(pf0, v0, O[dt], 0, 0, 0);
            O[dt] = __builtin_amdgcn_mfma_f32_16x16x32_bf16(pf1, v1, O[dt], 0, 0, 0);
        }
    }

    // write unnormalized partials (64 local rows per flat block id p)
    const size_t pbase = ((size_t)p * 7 + h) * 64;
#pragma unroll
    for (int dt = 0; dt < 8; dt++)
#pragma unroll
        for (int r = 0; r < 4; r++) {
            int lrow = w * 16 + quad * 4 + r;
            Opart[(pbase + lrow) * 128 + dt * 16 + lr] = bf1(O[dt][r]);
        }
    if (quad == 0) {   // softmax state lives at row = lr
        int lrow = w * 16 + lr;
        Lm[(pbase + lrow) * 2 + 0] = m;
        Lm[(pbase + lrow) * 2 + 1] = l;
    }
}

// ---------------------------------------------------------------------------
// Merge variable-count partials -> Ab (bf16). Grid (64,7), block 256.
// Thread = (local row = t>>2, 32-dim slice = (t&3)*32). Tile tt reads splits
// p in [P[tt], P[tt]+S(tt)), S <= MAXSPLIT; unroll-8 with guards keeps all
// array indexing static (no scratch).
// ---------------------------------------------------------------------------
__global__ __launch_bounds__(256)
void attn_merge(const ushort_t* __restrict__ Opart,
                const float* __restrict__ Lm,
                ushort_t* __restrict__ Ab) {
    const int h = blockIdx.y;
    const int tt = blockIdx.x;
    int pb = 0;
    for (int u = 0; u < tt; ++u) pb += nsplit_of(u);
    const int S = nsplit_of(tt);          // 1..8
    const int lrow = threadIdx.x >> 2;
    const int row = tt * 64 + lrow;
    const int d0 = (threadIdx.x & 3) * 32;

    float ms[MAXSPLIT], ls[MAXSPLIT], M = -1e30f;
#pragma unroll
    for (int s = 0; s < MAXSPLIT; s++) {
        ms[s] = -1e30f;
        ls[s] = 0.f;
        if (s < S) {
            size_t q = (((size_t)(pb + s) * 7 + h) * 64 + lrow) * 2;
            ms[s] = Lm[q];
            ls[s] = Lm[q + 1];
        }
        M = fmaxf(M, ms[s]);
    }
    float L = 0.f, c[MAXSPLIT];
#pragma unroll
    for (int s = 0; s < MAXSPLIT; s++) {
        c[s] = __expf(ms[s] - M);   // s>=S: exp(-1e30-M) == 0
        L += c[s] * ls[s];
    }
    float acc[32];
#pragma unroll
    for (int k = 0; k < 32; k++) acc[k] = 0.f;
#pragma unroll
    for (int s = 0; s < MAXSPLIT; s++) {
        if (s < S) {
            const float cs = c[s];
            const ushort_t* op =
                Opart + (((size_t)(pb + s) * 7 + h) * 64 + lrow) * 128 + d0;
#pragma unroll
            for (int v = 0; v < 4; v++) {
                uint4 u = *(const uint4*)(op + v * 8);
                acc[v * 8 + 0] += cs * lo_f(u.x);
                acc[v * 8 + 1] += cs * hi_f(u.x);
                acc[v * 8 + 2] += cs * lo_f(u.y);
                acc[v * 8 + 3] += cs * hi_f(u.y);
                acc[v * 8 + 4] += cs * lo_f(u.z);
                acc[v * 8 + 5] += cs * hi_f(u.z);
                acc[v * 8 + 6] += cs * lo_f(u.w);
                acc[v * 8 + 7] += cs * hi_f(u.w);
            }
        }
    }
    float invL = 1.f / L;   // L > 0: j==i lies in some split
    ushort_t* dst = Ab + (size_t)row * D_MODEL + h * 128 + d0;
#pragma unroll
    for (int v = 0; v < 4; v++) {
        uint4 u;
        u.x = f2bf(acc[v * 8 + 0] * invL) | (f2bf(acc[v * 8 + 1] * invL) << 16);
        u.y = f2bf(acc[v * 8 + 2] * invL) | (f2bf(acc[v * 8 + 3] * invL) << 16);
        u.z = f2bf(acc[v * 8 + 4] * invL) | (f2bf(acc[v * 8 + 5] * invL) << 16);
        u.w = f2bf(acc[v * 8 + 6] * invL) | (f2bf(acc[v * 8 + 7] * invL) << 16);
        *(uint4*)(dst + v * 8) = u;
    }
}

extern "C" void kernel_launch(void* const* d_in, const int* in_sizes, int n_in,
                              void* d_out, int out_size, void* d_ws, size_t ws_size,
                              hipStream_t stream) {
    const float* x  = (const float*)d_in[0];   // fp32 [4096, 896]
    const float* Wq = (const float*)d_in[1];   // fp32 [896, 896]
    const float* Wk = (const float*)d_in[2];
    const float* Wv = (const float*)d_in[3];
    const float* Wo = (const float*)d_in[4];

    // total attention blocks in the balanced schedule
    int NP = 0;
    for (int u = 0; u < 64; ++u) NP += nsplit_of(u);

    const size_t n  = (size_t)T_SEQ * D_MODEL;
    const size_t nw = (size_t)D_MODEL * D_MODEL;
    ushort_t* xb  = (ushort_t*)d_ws + 128;   // 256B offset
    ushort_t* Wqb = xb + n;
    ushort_t* Wkb = Wqb + nw;
    ushort_t* Wvb = Wkb + nw;
    ushort_t* Wob = Wvb + nw;
    ushort_t* Qb  = Wob + nw;
    ushort_t* Kb  = Qb + n;
    ushort_t* Vb  = Kb + n;
    ushort_t* Ab  = Vb + n;
    ushort_t* Opart = Ab + n;                          // NP*7*64*128 bf16
    float*    Lm  = (float*)(Opart + (size_t)NP * 7 * 64 * 128);

    // 0: fp32 -> bf16 bulk convert (x + 4 weights)
    cvt5<<<dim3(1792, 5), 256, 0, stream>>>(x, Wq, Wk, Wv, Wo,
                                            xb, Wqb, Wkb, Wvb, Wob);
    // 1: Q/K/V = x @ W^T (bf16, DMA-staged)
    gemm_nt_dma<false><<<dim3(32, 7, 3), 256, 0, stream>>>(
        xb, Wqb, Wkb, Wvb, Qb, Kb, Vb);
    // 2: balanced split-K sparse attention -> partials
    fano_attn_split<<<dim3(NP, 7), 256, 0, stream>>>(
        Qb, Kb, Vb, Opart, Lm);
    // 3: merge partials -> Ab
    attn_merge<<<dim3(64, 7), 256, 0, stream>>>(Opart, Lm, Ab);
    // 4: out = Ab @ Wo^T -> fp32
    gemm_nt_dma<true><<<dim3(32, 7, 1), 256, 0, stream>>>(
        Ab, Wob, Wob, Wob, d_out, d_out, d_out);
}

// Round 14
// 127.453 us; speedup vs baseline: 2.7571x; 2.7571x over previous
//
#include <hip/hip_runtime.h>
#include <stdint.h>

typedef unsigned short ushort_t;
typedef __bf16 bf16x8 __attribute__((ext_vector_type(8)));
typedef __bf16 bf16x2 __attribute__((ext_vector_type(2)));
typedef float f32x4 __attribute__((ext_vector_type(4)));

#define T_SEQ 4096
#define D_MODEL 896
#define CHUNKS_PER_BLOCK 4   // target chunks per attention block (balance quantum)
#define MAXSPLIT 8           // max splits per tile (t=63 -> 8)

// Attention LDS strides (u16 units, 8-multiples for ds_read_b128 alignment).
#define LSK 136   // 68 dwords/row
#define LSV 72    // 36 dwords/row; lane=key scatter spans all 32 banks

// Fano lines, residues sorted ascending per head
__constant__ int d_LINEMASK[7] = {0x07, 0x19, 0x61, 0x2A, 0x52, 0x4C, 0x34};
__constant__ int d_R[7][3] = {{0,1,2},{0,3,4},{0,5,6},{1,3,5},{1,4,6},{2,3,6},{2,4,5}};

__device__ inline unsigned f2bf(float f) {
    unsigned x = __float_as_uint(f);
    return (x + 0x7fffu + ((x >> 16) & 1u)) >> 16;   // RNE
}
__device__ inline float lo_f(unsigned x) { return __uint_as_float(x << 16); }
__device__ inline float hi_f(unsigned x) { return __uint_as_float(x & 0xFFFF0000u); }

// pack two f32 -> u32 of 2 bf16 via HW cvt (RNE; compiler emits v_cvt_pk_bf16_f32)
__device__ __forceinline__ unsigned pk_bf2(float lo, float hi) {
    union { bf16x2 h; unsigned u; } cv;
    cv.h = (bf16x2){(__bf16)lo, (__bf16)hi};
    return cv.u;
}
__device__ __forceinline__ ushort_t bf1(float f) {
    union { __bf16 h; ushort_t u; } cv;
    cv.h = (__bf16)f;
    return cv.u;
}

// ---------------------------------------------------------------------------
// Static balanced schedule (R11). Head-independent upper bound on the chunk
// count of tile t; split count S(t) = ceil(ntot_ub/CHUNKS_PER_BLOCK) so every
// attention block runs <= 4 chunks. Same formula on host (grid size) and
// device (tile lookup); all wave-uniform SALU.
// ---------------------------------------------------------------------------
__host__ __device__ inline int nsplit_of(int t) {
    int a = (192 * t + 189) / 7 + 3;        // >= any head's ncomp for this tile
    int nch_ub = (a + 63) >> 6;             // >= any head's nch
    return (nch_ub + 2 + CHUNKS_PER_BLOCK - 1) / CHUNKS_PER_BLOCK;  // ntot_ub/4
}

// ---------------------------------------------------------------------------
// fp32 -> bf16 bulk convert, 5 tensors (x, Wq, Wk, Wv, Wo). 8 elem/thread.
// ---------------------------------------------------------------------------
__global__ __launch_bounds__(256)
void cvt5(const float* __restrict__ x,  const float* __restrict__ wq,
          const float* __restrict__ wk, const float* __restrict__ wv,
          const float* __restrict__ wo,
          ushort_t* __restrict__ xb,  ushort_t* __restrict__ wqb,
          ushort_t* __restrict__ wkb, ushort_t* __restrict__ wvb,
          ushort_t* __restrict__ wob) {
    const int ten = blockIdx.y;
    const float* s = (ten == 0) ? x : (ten == 1) ? wq : (ten == 2) ? wk
                   : (ten == 3) ? wv : wo;
    ushort_t* d = (ten == 0) ? xb : (ten == 1) ? wqb : (ten == 2) ? wkb
                : (ten == 3) ? wvb : wob;
    const int n8 = ((ten == 0) ? T_SEQ * D_MODEL : D_MODEL * D_MODEL) >> 3;
    for (int i = blockIdx.x * 256 + threadIdx.x; i < n8; i += gridDim.x * 256) {
        float4 a = ((const float4*)s)[2 * i];
        float4 b = ((const float4*)s)[2 * i + 1];
        uint4 u;
        u.x = f2bf(a.x) | (f2bf(a.y) << 16);
        u.y = f2bf(a.z) | (f2bf(a.w) << 16);
        u.z = f2bf(b.x) | (f2bf(b.y) << 16);
        u.w = f2bf(b.z) | (f2bf(b.w) << 16);
        ((uint4*)d)[i] = u;
    }
}

// async global->LDS DMA, 16 B/lane. LDS dest = wave-uniform base + lane*16.
__device__ __forceinline__ void async_cp16(const void* g, void* l) {
    __builtin_amdgcn_global_load_lds(
        (__attribute__((address_space(1))) void*)g,
        (__attribute__((address_space(3))) void*)l,
        16, 0, 0);
}

// ---------------------------------------------------------------------------
// C[M,N] = A[M,K] @ B[N,K]^T, bf16 in, fp32 acc, bf16/fp32 out (R9-verified).
// m97 structure: 128x128 tile, BK=32, DMA staging. z selects (B,C) pair.
// ---------------------------------------------------------------------------
template <bool C32>
__global__ __launch_bounds__(256)
void gemm_nt_dma(const ushort_t* __restrict__ A,
                 const ushort_t* __restrict__ B0,
                 const ushort_t* __restrict__ B1,
                 const ushort_t* __restrict__ B2,
                 void* __restrict__ C0,
                 void* __restrict__ C1,
                 void* __restrict__ C2) {
    const int z = blockIdx.z;
    const ushort_t* B = (z == 0) ? B0 : (z == 1) ? B1 : B2;
    void* C = (z == 0) ? C0 : (z == 1) ? C1 : C2;

    const int K = D_MODEL, N = D_MODEL;
    const int i0 = blockIdx.x * 128;
    const int n0 = blockIdx.y * 128;

    __shared__ __align__(16) ushort_t As[128 * 32];   // NO padding (DMA layout)
    __shared__ __align__(16) ushort_t Bs[128 * 32];

    const int t = threadIdx.x;
    const int w = t >> 6, lane = t & 63;
    const int wm = (w >> 1) * 64, wn = (w & 1) * 64;
    const int lr = lane & 15, lq = lane >> 4;

    const int srow = w * 16 + (lane >> 2);
    const int scol = (lane & 3) * 8;
    const ushort_t* gA0 = A + (size_t)(i0 + srow) * K + scol;
    const ushort_t* gA1 = A + (size_t)(i0 + 64 + srow) * K + scol;
    const ushort_t* gB0 = B + (size_t)(n0 + srow) * K + scol;
    const ushort_t* gB1 = B + (size_t)(n0 + 64 + srow) * K + scol;
    ushort_t* lA0 = &As[(w * 16) * 32];
    ushort_t* lA1 = &As[(64 + w * 16) * 32];
    ushort_t* lB0 = &Bs[(w * 16) * 32];
    ushort_t* lB1 = &Bs[(64 + w * 16) * 32];

    f32x4 acc[4][4];
#pragma unroll
    for (int a = 0; a < 4; a++)
#pragma unroll
        for (int b = 0; b < 4; b++) acc[a][b] = (f32x4){0.f, 0.f, 0.f, 0.f};

    for (int k0 = 0; k0 < K; k0 += 32) {
        __syncthreads();
        async_cp16(gA0 + k0, lA0);
        async_cp16(gA1 + k0, lA1);
        async_cp16(gB0 + k0, lB0);
        async_cp16(gB1 + k0, lB1);
        __builtin_amdgcn_s_waitcnt(0);
        __syncthreads();

        bf16x8 af[4], bfr[4];
#pragma unroll
        for (int mi = 0; mi < 4; mi++)
            af[mi] = *(const bf16x8*)&As[(wm + mi * 16 + lr) * 32 + lq * 8];
#pragma unroll
        for (int ni = 0; ni < 4; ni++)
            bfr[ni] = *(const bf16x8*)&Bs[(wn + ni * 16 + lr) * 32 + lq * 8];
#pragma unroll
        for (int mi = 0; mi < 4; mi++)
#pragma unroll
            for (int ni = 0; ni < 4; ni++)
                acc[mi][ni] = __builtin_amdgcn_mfma_f32_16x16x32_bf16(
                    af[mi], bfr[ni], acc[mi][ni], 0, 0, 0);
    }

    // C/D layout: col = lane&15, row = (lane>>4)*4 + reg
    if (C32) {
        float* Cf = (float*)C;
#pragma unroll
        for (int mi = 0; mi < 4; mi++)
#pragma unroll
            for (int ni = 0; ni < 4; ni++)
#pragma unroll
                for (int r = 0; r < 4; r++) {
                    int row = i0 + wm + mi * 16 + lq * 4 + r;
                    int col = n0 + wn + ni * 16 + lr;
                    Cf[(size_t)row * N + col] = acc[mi][ni][r];
                }
    } else {
        ushort_t* Cb = (ushort_t*)C;
#pragma unroll
        for (int mi = 0; mi < 4; mi++)
#pragma unroll
            for (int ni = 0; ni < 4; ni++)
#pragma unroll
                for (int r = 0; r < 4; r++) {
                    int row = i0 + wm + mi * 16 + lq * 4 + r;
                    int col = n0 + wn + ni * 16 + lr;
                    Cb[(size_t)row * N + col] = (ushort_t)f2bf(acc[mi][ni][r]);
                }
    }
}

// scatter 8 dims of one key's V into Vt[d][key] (stride LSV); lane=key mapping
__device__ inline void vt_scatter8(ushort_t* vtcol, uint4 vv) {
    vtcol[0 * LSV] = (ushort_t)(vv.x & 0xFFFFu);
    vtcol[1 * LSV] = (ushort_t)(vv.x >> 16);
    vtcol[2 * LSV] = (ushort_t)(vv.y & 0xFFFFu);
    vtcol[3 * LSV] = (ushort_t)(vv.y >> 16);
    vtcol[4 * LSV] = (ushort_t)(vv.z & 0xFFFFu);
    vtcol[5 * LSV] = (ushort_t)(vv.z >> 16);
    vtcol[6 * LSV] = (ushort_t)(vv.w & 0xFFFFu);
    vtcol[7 * LSV] = (ushort_t)(vv.w >> 16);
}

// compacted-index -> key: p -> j = 7*(p/3) + r[p%3]
__device__ inline int jof(int p, int r0, int r1, int r2) {
    int g = p / 3, rs = p - 3 * g;
    return 7 * g + ((rs == 0) ? r0 : (rs == 1) ? r1 : r2);
}

// Direct staging (R9/R18/R20-proven): stage 32 dims of key j (slot kk) into
// Ks (row-major) and Vt (transposed). K first, then V, reusing the same 16
// temp VGPRs — minimal arch register peak. (R21 lesson: at (256,4) the
// compiler allocates exactly 64 arch regs for this kernel; holding ANY
// extra 16 prefetch regs spills. R20's direct staging fits exactly.)
__device__ __forceinline__ void stage_kv(const ushort_t* __restrict__ Kb,
                                         const ushort_t* __restrict__ Vb,
                                         ushort_t* Ks, ushort_t* Vt,
                                         int j, int kk, int dim0, int h) {
    if (j >= 0 && j < T_SEQ) {
        const ushort_t* kp = Kb + (size_t)j * D_MODEL + h * 128 + dim0;
#pragma unroll
        for (int v = 0; v < 4; v++)
            *(uint4*)&Ks[kk * LSK + dim0 + v * 8] = *(const uint4*)(kp + v * 8);
        const ushort_t* vp = Vb + (size_t)j * D_MODEL + h * 128 + dim0;
#pragma unroll
        for (int v = 0; v < 4; v++)
            vt_scatter8(&Vt[(dim0 + v * 8) * LSV + kk], *(const uint4*)(vp + v * 8));
    } else {
        uint4 zz = {0u, 0u, 0u, 0u};
#pragma unroll
        for (int v = 0; v < 4; v++) {
            *(uint4*)&Ks[kk * LSK + dim0 + v * 8] = zz;
            vt_scatter8(&Vt[(dim0 + v * 8) * LSV + kk], zz);
        }
    }
}

// ---------------------------------------------------------------------------
// Balanced split-K MFMA Fano attention (R22 = R20 + s_setprio on MFMA).
// Grid (NP, 7), NP = sum_t nsplit_of(t); every block runs <= 4 chunks.
//
// R20 baseline: 57.9 us attn, 4 blocks/CU (16 waves), VGPR 64 exact fit,
// no spill. R21 (K-prefetch at (256,4)) spilled — arch budget is exactly
// 64; no register headroom exists at this occupancy.
// R22 adds T5 s_setprio(1) around the QK^T and PV MFMA clusters: 4
// independent blocks/CU with no cross-block sync -> waves sit at different
// phases (staging vs compute); boosting MFMA-phase waves' issue priority
// measured +4-7% on the same independent-block attn regime (m191).
// Zero registers, zero layout change.
//
// Structure (R12-R14, verified): S^T = mfma(A=K, B=Q); lane (lr,quad)
// holds S[q-row=lr][key=tn*16+quad*4+r]; in-lane softmax; in-register
// P->A-frag shuffle; no Ps LDS; interior fast-path; HW bf16 cvt; THR=8
// defer-max. Direct staging between the two barriers.
// ---------------------------------------------------------------------------
__global__ __launch_bounds__(256, 4)
void fano_attn_split(const ushort_t* __restrict__ Qb,
                     const ushort_t* __restrict__ Kb,
                     const ushort_t* __restrict__ Vb,
                     ushort_t* __restrict__ Opart,
                     float* __restrict__ Lm) {
    const int h = blockIdx.y;
    const int p = (int)gridDim.x - 1 - (int)blockIdx.x;  // LPT: big tiles first

    // tile lookup: find t with P[t] <= p < P[t]+S(t)  (wave-uniform)
    int tile = 63, pbase0 = 0;
    for (int u = 0; u < 64; ++u) {
        int s = nsplit_of(u);
        if (p < pbase0 + s) { tile = u; break; }
        pbase0 += s;
    }
    const int sp = p - pbase0;            // split index within tile
    const int Sloc = nsplit_of(tile);

    const int i0 = tile * 64;
    const int t = threadIdx.x;
    const int w = t >> 6, lane = t & 63;
    const int lr = lane & 15, quad = lane >> 4;
    const int iw0 = i0 + w * 16;

    __shared__ __align__(16) ushort_t Ks[64 * LSK];   // 17408 B
    __shared__ __align__(16) ushort_t Vt[128 * LSV];  // 18432 B

    const int lm = d_LINEMASK[h];
    const int r0 = d_R[h][0], r1 = d_R[h][1], r2 = d_R[h][2];
    const float scale = 0.08838834764831845f;

    // Q B-frags: lane holds Q[iw0+lr][f*32 + quad*8 + (0..7)]
    bf16x8 qf[4];
    {
        const ushort_t* qrow = Qb + (size_t)(iw0 + lr) * D_MODEL + h * 128;
#pragma unroll
        for (int f = 0; f < 4; f++)
            qf[f] = *(const bf16x8*)(qrow + f * 32 + quad * 8);
    }

    f32x4 O[8];
#pragma unroll
    for (int dt = 0; dt < 8; dt++) O[dt] = (f32x4){0.f, 0.f, 0.f, 0.f};
    float m = -1e30f;   // running max of q-row (iw0 + lr)
    float l = 0.f;      // running sum of q-row (iw0 + lr)

    const int imax = i0 + 63;
    const int ncomp = (imax - r0) / 7 + (imax - r1) / 7 + (imax - r2) / 7 + 3;
    const int nch = (ncomp + 63) >> 6;
    const int ntot = nch + 2;                // + two linear band chunks
    const int cstart = (sp * ntot) / Sloc;   // this split's chunk sub-range
    const int cend = ((sp + 1) * ntot) / Sloc;

    // per-lane key index for chunk cc (staging gather; lane = key slot)
    auto chunk_j = [&](int cc) -> int {
        if (cc >= nch) {
            const int jbase = (cc == nch) ? i0 - 16 : i0 + 48;
            return jbase + lane;
        }
        return jof(cc * 64 + lane, r0, r1, r2);
    };

    const int iq = iw0 + lr;   // this lane's q-row

    for (int cc = cstart; cc < cend; cc++) {
        const bool band = (cc >= nch);
        const int jbase = (cc == nch) ? i0 - 16 : i0 + 48;

        __syncthreads();   // #1: prev chunk's LDS reads complete
        stage_kv(Kb, Vb, Ks, Vt, chunk_j(cc), lane, w * 32, h);
        __syncthreads();   // #2: staging visible to all waves

        // wave-uniform skip: chunk min j beyond this wave's rows
        {
            int jmin = band ? jbase : jof(cc * 64, r0, r1, r2);
            if (jmin > iw0 + 15) continue;
        }

        // S^T = K Q^T over 4 tiles of 16 keys (swapped operands)
        f32x4 S[4];
#pragma unroll
        for (int tn = 0; tn < 4; tn++) S[tn] = (f32x4){0.f, 0.f, 0.f, 0.f};
        __builtin_amdgcn_s_setprio(1);   // T5: favor MFMA-phase waves
#pragma unroll
        for (int f = 0; f < 4; f++) {
            bf16x8 kf[4];
#pragma unroll
            for (int tn = 0; tn < 4; tn++)
                kf[tn] = *(const bf16x8*)&Ks[(tn * 16 + lr) * LSK + f * 32 + quad * 8];
#pragma unroll
            for (int tn = 0; tn < 4; tn++)
                S[tn] = __builtin_amdgcn_mfma_f32_16x16x32_bf16(kf[tn], qf[f], S[tn], 0, 0, 0);
        }
        __builtin_amdgcn_s_setprio(0);

        // mask: lane holds S[q=iq][key = tn*16 + quad*4 + r].
        // Fast path (wave-uniform): interior fano chunk — every key <=
        // every row of this wave, keys are line-members by construction.
        const bool interior = !band && (jof(cc * 64 + 63, r0, r1, r2) <= iw0);
        if (interior) {
#pragma unroll
            for (int tn = 0; tn < 4; tn++)
#pragma unroll
                for (int r = 0; r < 4; r++) S[tn][r] *= scale;
        } else if (band) {
            // band: 0<=j<=i, j>=i-16, j%7 not in line (disjoint from fano)
#pragma unroll
            for (int tn = 0; tn < 4; tn++)
#pragma unroll
                for (int r = 0; r < 4; r++) {
                    int j = jbase + tn * 16 + quad * 4 + r;
                    int jm = ((j % 7) + 7) % 7;
                    bool ok = (j >= 0) && !((lm >> jm) & 1) &&
                              (j <= iq) && (j >= iq - 16);
                    S[tn][r] = ok ? S[tn][r] * scale : -1e30f;
                }
        } else {
            // straddling fano chunk: causal mask only
#pragma unroll
            for (int tn = 0; tn < 4; tn++) {
                int p0 = cc * 64 + tn * 16 + quad * 4;
                int g = p0 / 3, rs = p0 - 3 * g;
#pragma unroll
                for (int r = 0; r < 4; r++) {
                    int j = 7 * g + ((rs == 0) ? r0 : (rs == 1) ? r1 : r2);
                    S[tn][r] = (j <= iq) ? S[tn][r] * scale : -1e30f;
                    if (++rs == 3) { rs = 0; ++g; }
                }
            }
        }

        // online softmax: row = lr (lane-local 16 values + cross-quad reduce)
        float cm = -1e30f;
#pragma unroll
        for (int tn = 0; tn < 4; tn++)
#pragma unroll
            for (int r = 0; r < 4; r++) cm = fmaxf(cm, S[tn][r]);
        cm = fmaxf(cm, __shfl_xor(cm, 16));
        cm = fmaxf(cm, __shfl_xor(cm, 32));

        // T13 defer-max, THR=8: skip rescale when max growth <= 8 for all
        // rows in the wave; P bounded by e^8, bf16/f32-safe. The m >= -60
        // guard keeps all-masked rows on the exact path.
        const bool defer = __all(cm <= m + 8.f && m >= -60.f);
        float mn, a = 1.f;
        if (defer) {
            mn = m;
        } else {
            mn = fmaxf(fmaxf(m, cm), -60.f);   // all-masked -> exact 0
            a = __expf(m - mn);
            m = mn;
        }
        float pr[4][4];
        float rs_ = 0.f;
#pragma unroll
        for (int tn = 0; tn < 4; tn++)
#pragma unroll
            for (int r = 0; r < 4; r++) {
                pr[tn][r] = __expf(S[tn][r] - mn);
                rs_ += pr[tn][r];
            }
        rs_ += __shfl_xor(rs_, 16);
        rs_ += __shfl_xor(rs_, 32);
        if (defer) {
            l = l + rs_;
        } else {
            l = l * a + rs_;
            // O-rescale: O rows are quad*4+r; row's a from lane (quad*4+r)
            float a4[4];
#pragma unroll
            for (int r = 0; r < 4; r++) a4[r] = __shfl(a, quad * 4 + r);
#pragma unroll
            for (int dt = 0; dt < 8; dt++)
#pragma unroll
                for (int r = 0; r < 4; r++) O[dt][r] *= a4[r];
        }

        // P -> PV A-frag, in-register (16 shfl + 8 selects; no LDS).
        // lane (lr,quad) holds P[lr][tn*16+quad*4+r]; target needs
        // P[lr][quad*8..+7] (pf0) and P[lr][32+quad*8..+7] (pf1), which live
        // in lanes srcA=32*(quad&1)+lr (r=0..3) and srcB=srcA+16 (r=0..3).
        unsigned u01[4], u23[4];
#pragma unroll
        for (int tn = 0; tn < 4; tn++) {
            u01[tn] = pk_bf2(pr[tn][0], pr[tn][1]);
            u23[tn] = pk_bf2(pr[tn][2], pr[tn][3]);
        }
        const int srcA = 32 * (quad & 1) + lr;
        const int srcB = srcA + 16;
        const bool hi = (quad >= 2);
        uint4 t0, t1;
        {
            unsigned d0a = __shfl(u01[0], srcA), d0b = __shfl(u01[1], srcA);
            unsigned d1a = __shfl(u23[0], srcA), d1b = __shfl(u23[1], srcA);
            unsigned d2a = __shfl(u01[0], srcB), d2b = __shfl(u01[1], srcB);
            unsigned d3a = __shfl(u23[0], srcB), d3b = __shfl(u23[1], srcB);
            t0.x = hi ? d0b : d0a;
            t0.y = hi ? d1b : d1a;
            t0.z = hi ? d2b : d2a;
            t0.w = hi ? d3b : d3a;
        }
        {
            unsigned d0a = __shfl(u01[2], srcA), d0b = __shfl(u01[3], srcA);
            unsigned d1a = __shfl(u23[2], srcA), d1b = __shfl(u23[3], srcA);
            unsigned d2a = __shfl(u01[2], srcB), d2b = __shfl(u01[3], srcB);
            unsigned d3a = __shfl(u23[2], srcB), d3b = __shfl(u23[3], srcB);
            t1.x = hi ? d0b : d0a;
            t1.y = hi ? d1b : d1a;
            t1.z = hi ? d2b : d2a;
            t1.w = hi ? d3b : d3a;
        }
        bf16x8 pf0 = *(const bf16x8*)&t0;
        bf16x8 pf1 = *(const bf16x8*)&t1;

        __builtin_amdgcn_s_setprio(1);   // T5: favor MFMA-phase waves
#pragma unroll
        for (int dt = 0; dt < 8; dt++) {
            bf16x8 v0 = *(const bf16x8*)&Vt[(dt * 16 + lr) * LSV + quad * 8];
            bf16x8 v1 = *(const bf16x8*)&Vt[(dt * 16 + lr) * LSV + 32 + quad * 8];
            O[dt] = __builtin_amdgcn_mfma_f32_16x16x32_bf16(pf0, v0, O[dt], 0, 0, 0);
            O[dt] = __builtin_amdgcn_mfma_f32_16x16x32_bf16(pf1, v1, O[dt], 0, 0, 0);
        }
        __builtin_amdgcn_s_setprio(0);
    }

    // write unnormalized partials (64 local rows per flat block id p)
    const size_t pbase = ((size_t)p * 7 + h) * 64;
#pragma unroll
    for (int dt = 0; dt < 8; dt++)
#pragma unroll
        for (int r = 0; r < 4; r++) {
            int lrow = w * 16 + quad * 4 + r;
            Opart[(pbase + lrow) * 128 + dt * 16 + lr] = bf1(O[dt][r]);
        }
    if (quad == 0) {   // softmax state lives at row = lr
        int lrow = w * 16 + lr;
        Lm[(pbase + lrow) * 2 + 0] = m;
        Lm[(pbase + lrow) * 2 + 1] = l;
    }
}

// ---------------------------------------------------------------------------
// Merge variable-count partials -> Ab (bf16). Grid (64,7), block 256.
// Thread = (local row = t>>2, 32-dim slice = (t&3)*32). Tile tt reads splits
// p in [P[tt], P[tt]+S(tt)), S <= MAXSPLIT; unroll-8 with guards keeps all
// array indexing static (no scratch).
// ---------------------------------------------------------------------------
__global__ __launch_bounds__(256)
void attn_merge(const ushort_t* __restrict__ Opart,
                const float* __restrict__ Lm,
                ushort_t* __restrict__ Ab) {
    const int h = blockIdx.y;
    const int tt = blockIdx.x;
    int pb = 0;
    for (int u = 0; u < tt; ++u) pb += nsplit_of(u);
    const int S = nsplit_of(tt);          // 1..8
    const int lrow = threadIdx.x >> 2;
    const int row = tt * 64 + lrow;
    const int d0 = (threadIdx.x & 3) * 32;

    float ms[MAXSPLIT], ls[MAXSPLIT], M = -1e30f;
#pragma unroll
    for (int s = 0; s < MAXSPLIT; s++) {
        ms[s] = -1e30f;
        ls[s] = 0.f;
        if (s < S) {
            size_t q = (((size_t)(pb + s) * 7 + h) * 64 + lrow) * 2;
            ms[s] = Lm[q];
            ls[s] = Lm[q + 1];
        }
        M = fmaxf(M, ms[s]);
    }
    float L = 0.f, c[MAXSPLIT];
#pragma unroll
    for (int s = 0; s < MAXSPLIT; s++) {
        c[s] = __expf(ms[s] - M);   // s>=S: exp(-1e30-M) == 0
        L += c[s] * ls[s];
    }
    float acc[32];
#pragma unroll
    for (int k = 0; k < 32; k++) acc[k] = 0.f;
#pragma unroll
    for (int s = 0; s < MAXSPLIT; s++) {
        if (s < S) {
            const float cs = c[s];
            const ushort_t* op =
                Opart + (((size_t)(pb + s) * 7 + h) * 64 + lrow) * 128 + d0;
#pragma unroll
            for (int v = 0; v < 4; v++) {
                uint4 u = *(const uint4*)(op + v * 8);
                acc[v * 8 + 0] += cs * lo_f(u.x);
                acc[v * 8 + 1] += cs * hi_f(u.x);
                acc[v * 8 + 2] += cs * lo_f(u.y);
                acc[v * 8 + 3] += cs * hi_f(u.y);
                acc[v * 8 + 4] += cs * lo_f(u.z);
                acc[v * 8 + 5] += cs * hi_f(u.z);
                acc[v * 8 + 6] += cs * lo_f(u.w);
                acc[v * 8 + 7] += cs * hi_f(u.w);
            }
        }
    }
    float invL = 1.f / L;   // L > 0: j==i lies in some split
    ushort_t* dst = Ab + (size_t)row * D_MODEL + h * 128 + d0;
#pragma unroll
    for (int v = 0; v < 4; v++) {
        uint4 u;
        u.x = f2bf(acc[v * 8 + 0] * invL) | (f2bf(acc[v * 8 + 1] * invL) << 16);
        u.y = f2bf(acc[v * 8 + 2] * invL) | (f2bf(acc[v * 8 + 3] * invL) << 16);
        u.z = f2bf(acc[v * 8 + 4] * invL) | (f2bf(acc[v * 8 + 5] * invL) << 16);
        u.w = f2bf(acc[v * 8 + 6] * invL) | (f2bf(acc[v * 8 + 7] * invL) << 16);
        *(uint4*)(dst + v * 8) = u;
    }
}

extern "C" void kernel_launch(void* const* d_in, const int* in_sizes, int n_in,
                              void* d_out, int out_size, void* d_ws, size_t ws_size,
                              hipStream_t stream) {
    const float* x  = (const float*)d_in[0];   // fp32 [4096, 896]
    const float* Wq = (const float*)d_in[1];   // fp32 [896, 896]
    const float* Wk = (const float*)d_in[2];
    const float* Wv = (const float*)d_in[3];
    const float* Wo = (const float*)d_in[4];

    // total attention blocks in the balanced schedule
    int NP = 0;
    for (int u = 0; u < 64; ++u) NP += nsplit_of(u);

    const size_t n  = (size_t)T_SEQ * D_MODEL;
    const size_t nw = (size_t)D_MODEL * D_MODEL;
    ushort_t* xb  = (ushort_t*)d_ws + 128;   // 256B offset
    ushort_t* Wqb = xb + n;
    ushort_t* Wkb = Wqb + nw;
    ushort_t* Wvb = Wkb + nw;
    ushort_t* Wob = Wvb + nw;
    ushort_t* Qb  = Wob + nw;
    ushort_t* Kb  = Qb + n;
    ushort_t* Vb  = Kb + n;
    ushort_t* Ab  = Vb + n;
    ushort_t* Opart = Ab + n;                          // NP*7*64*128 bf16
    float*    Lm  = (float*)(Opart + (size_t)NP * 7 * 64 * 128);

    // 0: fp32 -> bf16 bulk convert (x + 4 weights)
    cvt5<<<dim3(1792, 5), 256, 0, stream>>>(x, Wq, Wk, Wv, Wo,
                                            xb, Wqb, Wkb, Wvb, Wob);
    // 1: Q/K/V = x @ W^T (bf16, DMA-staged)
    gemm_nt_dma<false><<<dim3(32, 7, 3), 256, 0, stream>>>(
        xb, Wqb, Wkb, Wvb, Qb, Kb, Vb);
    // 2: balanced split-K sparse attention -> partials
    fano_attn_split<<<dim3(NP, 7), 256, 0, stream>>>(
        Qb, Kb, Vb, Opart, Lm);
    // 3: merge partials -> Ab
    attn_merge<<<dim3(64, 7), 256, 0, stream>>>(Opart, Lm, Ab);
    // 4: out = Ab @ Wo^T -> fp32
    gemm_nt_dma<true><<<dim3(32, 7, 1), 256, 0, stream>>>(
        Ab, Wob, Wob, Wob, d_out, d_out, d_out);
}

// Round 15
// 124.429 us; speedup vs baseline: 2.8241x; 1.0243x over previous
//
#include <hip/hip_runtime.h>
#include <stdint.h>

typedef unsigned short ushort_t;
typedef __bf16 bf16x8 __attribute__((ext_vector_type(8)));
typedef __bf16 bf16x2 __attribute__((ext_vector_type(2)));
typedef float f32x4 __attribute__((ext_vector_type(4)));

#define T_SEQ 4096
#define D_MODEL 896
#define CHUNKS_PER_BLOCK 4   // target chunks per attention block (balance quantum)
#define MAXSPLIT 8           // max splits per tile (t=63 -> 8)

// Attention LDS strides (u16 units, 8-multiples for ds_read_b128 alignment).
#define LSK 136   // 68 dwords/row
#define LSV 72    // 36 dwords/row; lane=key scatter spans all 32 banks

// Fano lines, residues sorted ascending per head
__constant__ int d_LINEMASK[7] = {0x07, 0x19, 0x61, 0x2A, 0x52, 0x4C, 0x34};
__constant__ int d_R[7][3] = {{0,1,2},{0,3,4},{0,5,6},{1,3,5},{1,4,6},{2,3,6},{2,4,5}};

__device__ inline unsigned f2bf(float f) {
    unsigned x = __float_as_uint(f);
    return (x + 0x7fffu + ((x >> 16) & 1u)) >> 16;   // RNE
}
__device__ inline float lo_f(unsigned x) { return __uint_as_float(x << 16); }
__device__ inline float hi_f(unsigned x) { return __uint_as_float(x & 0xFFFF0000u); }

// pack two f32 -> u32 of 2 bf16 via HW cvt (RNE; compiler emits v_cvt_pk_bf16_f32)
__device__ __forceinline__ unsigned pk_bf2(float lo, float hi) {
    union { bf16x2 h; unsigned u; } cv;
    cv.h = (bf16x2){(__bf16)lo, (__bf16)hi};
    return cv.u;
}
__device__ __forceinline__ ushort_t bf1(float f) {
    union { __bf16 h; ushort_t u; } cv;
    cv.h = (__bf16)f;
    return cv.u;
}

// ---------------------------------------------------------------------------
// Static balanced schedule (R11). Head-independent upper bound on the chunk
// count of tile t; split count S(t) = ceil(ntot_ub/CHUNKS_PER_BLOCK) so every
// attention block runs <= 4 chunks. Same formula on host (grid size) and
// device (tile lookup); all wave-uniform SALU.
// ---------------------------------------------------------------------------
__host__ __device__ inline int nsplit_of(int t) {
    int a = (192 * t + 189) / 7 + 3;        // >= any head's ncomp for this tile
    int nch_ub = (a + 63) >> 6;             // >= any head's nch
    return (nch_ub + 2 + CHUNKS_PER_BLOCK - 1) / CHUNKS_PER_BLOCK;  // ntot_ub/4
}

// ---------------------------------------------------------------------------
// fp32 -> bf16 bulk convert, 5 tensors (x, Wq, Wk, Wv, Wo). 8 elem/thread.
// ---------------------------------------------------------------------------
__global__ __launch_bounds__(256)
void cvt5(const float* __restrict__ x,  const float* __restrict__ wq,
          const float* __restrict__ wk, const float* __restrict__ wv,
          const float* __restrict__ wo,
          ushort_t* __restrict__ xb,  ushort_t* __restrict__ wqb,
          ushort_t* __restrict__ wkb, ushort_t* __restrict__ wvb,
          ushort_t* __restrict__ wob) {
    const int ten = blockIdx.y;
    const float* s = (ten == 0) ? x : (ten == 1) ? wq : (ten == 2) ? wk
                   : (ten == 3) ? wv : wo;
    ushort_t* d = (ten == 0) ? xb : (ten == 1) ? wqb : (ten == 2) ? wkb
                : (ten == 3) ? wvb : wob;
    const int n8 = ((ten == 0) ? T_SEQ * D_MODEL : D_MODEL * D_MODEL) >> 3;
    for (int i = blockIdx.x * 256 + threadIdx.x; i < n8; i += gridDim.x * 256) {
        float4 a = ((const float4*)s)[2 * i];
        float4 b = ((const float4*)s)[2 * i + 1];
        uint4 u;
        u.x = f2bf(a.x) | (f2bf(a.y) << 16);
        u.y = f2bf(a.z) | (f2bf(a.w) << 16);
        u.z = f2bf(b.x) | (f2bf(b.y) << 16);
        u.w = f2bf(b.z) | (f2bf(b.w) << 16);
        ((uint4*)d)[i] = u;
    }
}

// async global->LDS DMA, 16 B/lane. LDS dest = wave-uniform base + lane*16.
__device__ __forceinline__ void async_cp16(const void* g, void* l) {
    __builtin_amdgcn_global_load_lds(
        (__attribute__((address_space(1))) void*)g,
        (__attribute__((address_space(3))) void*)l,
        16, 0, 0);
}

// ---------------------------------------------------------------------------
// C[M,N] = A[M,K] @ B[N,K]^T, bf16 in, fp32 acc, bf16/fp32 out (R9-verified).
// m97 structure: 128x128 tile, BK=32, DMA staging. z selects (B,C) pair.
// R23: __launch_bounds__(256,4) — live set ~110 (64 accum + ~45 arch) fits
// the 128-reg budget (same exact-fit regime as the attn kernel at (256,4));
// LDS 16 KB x 4 = 64 KB. 4 blocks/CU lets other blocks' MFMA cover each
// block's per-K-step vmcnt(0)+barrier drain (28 short K-steps at K=896).
// ---------------------------------------------------------------------------
template <bool C32>
__global__ __launch_bounds__(256, 4)
void gemm_nt_dma(const ushort_t* __restrict__ A,
                 const ushort_t* __restrict__ B0,
                 const ushort_t* __restrict__ B1,
                 const ushort_t* __restrict__ B2,
                 void* __restrict__ C0,
                 void* __restrict__ C1,
                 void* __restrict__ C2) {
    const int z = blockIdx.z;
    const ushort_t* B = (z == 0) ? B0 : (z == 1) ? B1 : B2;
    void* C = (z == 0) ? C0 : (z == 1) ? C1 : C2;

    const int K = D_MODEL, N = D_MODEL;
    const int i0 = blockIdx.x * 128;
    const int n0 = blockIdx.y * 128;

    __shared__ __align__(16) ushort_t As[128 * 32];   // NO padding (DMA layout)
    __shared__ __align__(16) ushort_t Bs[128 * 32];

    const int t = threadIdx.x;
    const int w = t >> 6, lane = t & 63;
    const int wm = (w >> 1) * 64, wn = (w & 1) * 64;
    const int lr = lane & 15, lq = lane >> 4;

    const int srow = w * 16 + (lane >> 2);
    const int scol = (lane & 3) * 8;
    const ushort_t* gA0 = A + (size_t)(i0 + srow) * K + scol;
    const ushort_t* gA1 = A + (size_t)(i0 + 64 + srow) * K + scol;
    const ushort_t* gB0 = B + (size_t)(n0 + srow) * K + scol;
    const ushort_t* gB1 = B + (size_t)(n0 + 64 + srow) * K + scol;
    ushort_t* lA0 = &As[(w * 16) * 32];
    ushort_t* lA1 = &As[(64 + w * 16) * 32];
    ushort_t* lB0 = &Bs[(w * 16) * 32];
    ushort_t* lB1 = &Bs[(64 + w * 16) * 32];

    f32x4 acc[4][4];
#pragma unroll
    for (int a = 0; a < 4; a++)
#pragma unroll
        for (int b = 0; b < 4; b++) acc[a][b] = (f32x4){0.f, 0.f, 0.f, 0.f};

    for (int k0 = 0; k0 < K; k0 += 32) {
        __syncthreads();
        async_cp16(gA0 + k0, lA0);
        async_cp16(gA1 + k0, lA1);
        async_cp16(gB0 + k0, lB0);
        async_cp16(gB1 + k0, lB1);
        __builtin_amdgcn_s_waitcnt(0);
        __syncthreads();

        bf16x8 af[4], bfr[4];
#pragma unroll
        for (int mi = 0; mi < 4; mi++)
            af[mi] = *(const bf16x8*)&As[(wm + mi * 16 + lr) * 32 + lq * 8];
#pragma unroll
        for (int ni = 0; ni < 4; ni++)
            bfr[ni] = *(const bf16x8*)&Bs[(wn + ni * 16 + lr) * 32 + lq * 8];
#pragma unroll
        for (int mi = 0; mi < 4; mi++)
#pragma unroll
            for (int ni = 0; ni < 4; ni++)
                acc[mi][ni] = __builtin_amdgcn_mfma_f32_16x16x32_bf16(
                    af[mi], bfr[ni], acc[mi][ni], 0, 0, 0);
    }

    // C/D layout: col = lane&15, row = (lane>>4)*4 + reg
    if (C32) {
        float* Cf = (float*)C;
#pragma unroll
        for (int mi = 0; mi < 4; mi++)
#pragma unroll
            for (int ni = 0; ni < 4; ni++)
#pragma unroll
                for (int r = 0; r < 4; r++) {
                    int row = i0 + wm + mi * 16 + lq * 4 + r;
                    int col = n0 + wn + ni * 16 + lr;
                    Cf[(size_t)row * N + col] = acc[mi][ni][r];
                }
    } else {
        ushort_t* Cb = (ushort_t*)C;
#pragma unroll
        for (int mi = 0; mi < 4; mi++)
#pragma unroll
            for (int ni = 0; ni < 4; ni++)
#pragma unroll
                for (int r = 0; r < 4; r++) {
                    int row = i0 + wm + mi * 16 + lq * 4 + r;
                    int col = n0 + wn + ni * 16 + lr;
                    Cb[(size_t)row * N + col] = (ushort_t)f2bf(acc[mi][ni][r]);
                }
    }
}

// scatter 8 dims of one key's V into Vt[d][key] (stride LSV); lane=key mapping
__device__ inline void vt_scatter8(ushort_t* vtcol, uint4 vv) {
    vtcol[0 * LSV] = (ushort_t)(vv.x & 0xFFFFu);
    vtcol[1 * LSV] = (ushort_t)(vv.x >> 16);
    vtcol[2 * LSV] = (ushort_t)(vv.y & 0xFFFFu);
    vtcol[3 * LSV] = (ushort_t)(vv.y >> 16);
    vtcol[4 * LSV] = (ushort_t)(vv.z & 0xFFFFu);
    vtcol[5 * LSV] = (ushort_t)(vv.z >> 16);
    vtcol[6 * LSV] = (ushort_t)(vv.w & 0xFFFFu);
    vtcol[7 * LSV] = (ushort_t)(vv.w >> 16);
}

// compacted-index -> key: p -> j = 7*(p/3) + r[p%3]
__device__ inline int jof(int p, int r0, int r1, int r2) {
    int g = p / 3, rs = p - 3 * g;
    return 7 * g + ((rs == 0) ? r0 : (rs == 1) ? r1 : r2);
}

// Direct staging (R9/R18/R20-proven): stage 32 dims of key j (slot kk) into
// Ks (row-major) and Vt (transposed). K first, then V, reusing the same 16
// temp VGPRs — minimal arch register peak. (R21 lesson: at (256,4) the
// compiler allocates exactly 64 arch regs for this kernel; holding ANY
// extra 16 prefetch regs spills. R20's direct staging fits exactly.)
__device__ __forceinline__ void stage_kv(const ushort_t* __restrict__ Kb,
                                         const ushort_t* __restrict__ Vb,
                                         ushort_t* Ks, ushort_t* Vt,
                                         int j, int kk, int dim0, int h) {
    if (j >= 0 && j < T_SEQ) {
        const ushort_t* kp = Kb + (size_t)j * D_MODEL + h * 128 + dim0;
#pragma unroll
        for (int v = 0; v < 4; v++)
            *(uint4*)&Ks[kk * LSK + dim0 + v * 8] = *(const uint4*)(kp + v * 8);
        const ushort_t* vp = Vb + (size_t)j * D_MODEL + h * 128 + dim0;
#pragma unroll
        for (int v = 0; v < 4; v++)
            vt_scatter8(&Vt[(dim0 + v * 8) * LSV + kk], *(const uint4*)(vp + v * 8));
    } else {
        uint4 zz = {0u, 0u, 0u, 0u};
#pragma unroll
        for (int v = 0; v < 4; v++) {
            *(uint4*)&Ks[kk * LSK + dim0 + v * 8] = zz;
            vt_scatter8(&Vt[(dim0 + v * 8) * LSV + kk], zz);
        }
    }
}

// ---------------------------------------------------------------------------
// Balanced split-K MFMA Fano attention (R23 attn = R20 verbatim; setprio
// removed — R22 measured it null on this barrier-locked structure).
// Grid (NP, 7), NP = sum_t nsplit_of(t); every block runs <= 4 chunks.
//
// R20: 57.9 us attn, 4 blocks/CU (16 waves), VGPR 64 exact fit, no spill.
// Register headroom at (256,4) is ZERO (R21/R22 evidence) — no prefetch.
//
// Structure (R12-R14, verified): S^T = mfma(A=K, B=Q); lane (lr,quad)
// holds S[q-row=lr][key=tn*16+quad*4+r]; in-lane softmax; in-register
// P->A-frag shuffle; no Ps LDS; interior fast-path; HW bf16 cvt; THR=8
// defer-max. Direct staging between the two barriers.
// ---------------------------------------------------------------------------
__global__ __launch_bounds__(256, 4)
void fano_attn_split(const ushort_t* __restrict__ Qb,
                     const ushort_t* __restrict__ Kb,
                     const ushort_t* __restrict__ Vb,
                     ushort_t* __restrict__ Opart,
                     float* __restrict__ Lm) {
    const int h = blockIdx.y;
    const int p = (int)gridDim.x - 1 - (int)blockIdx.x;  // LPT: big tiles first

    // tile lookup: find t with P[t] <= p < P[t]+S(t)  (wave-uniform)
    int tile = 63, pbase0 = 0;
    for (int u = 0; u < 64; ++u) {
        int s = nsplit_of(u);
        if (p < pbase0 + s) { tile = u; break; }
        pbase0 += s;
    }
    const int sp = p - pbase0;            // split index within tile
    const int Sloc = nsplit_of(tile);

    const int i0 = tile * 64;
    const int t = threadIdx.x;
    const int w = t >> 6, lane = t & 63;
    const int lr = lane & 15, quad = lane >> 4;
    const int iw0 = i0 + w * 16;

    __shared__ __align__(16) ushort_t Ks[64 * LSK];   // 17408 B
    __shared__ __align__(16) ushort_t Vt[128 * LSV];  // 18432 B

    const int lm = d_LINEMASK[h];
    const int r0 = d_R[h][0], r1 = d_R[h][1], r2 = d_R[h][2];
    const float scale = 0.08838834764831845f;

    // Q B-frags: lane holds Q[iw0+lr][f*32 + quad*8 + (0..7)]
    bf16x8 qf[4];
    {
        const ushort_t* qrow = Qb + (size_t)(iw0 + lr) * D_MODEL + h * 128;
#pragma unroll
        for (int f = 0; f < 4; f++)
            qf[f] = *(const bf16x8*)(qrow + f * 32 + quad * 8);
    }

    f32x4 O[8];
#pragma unroll
    for (int dt = 0; dt < 8; dt++) O[dt] = (f32x4){0.f, 0.f, 0.f, 0.f};
    float m = -1e30f;   // running max of q-row (iw0 + lr)
    float l = 0.f;      // running sum of q-row (iw0 + lr)

    const int imax = i0 + 63;
    const int ncomp = (imax - r0) / 7 + (imax - r1) / 7 + (imax - r2) / 7 + 3;
    const int nch = (ncomp + 63) >> 6;
    const int ntot = nch + 2;                // + two linear band chunks
    const int cstart = (sp * ntot) / Sloc;   // this split's chunk sub-range
    const int cend = ((sp + 1) * ntot) / Sloc;

    // per-lane key index for chunk cc (staging gather; lane = key slot)
    auto chunk_j = [&](int cc) -> int {
        if (cc >= nch) {
            const int jbase = (cc == nch) ? i0 - 16 : i0 + 48;
            return jbase + lane;
        }
        return jof(cc * 64 + lane, r0, r1, r2);
    };

    const int iq = iw0 + lr;   // this lane's q-row

    for (int cc = cstart; cc < cend; cc++) {
        const bool band = (cc >= nch);
        const int jbase = (cc == nch) ? i0 - 16 : i0 + 48;

        __syncthreads();   // #1: prev chunk's LDS reads complete
        stage_kv(Kb, Vb, Ks, Vt, chunk_j(cc), lane, w * 32, h);
        __syncthreads();   // #2: staging visible to all waves

        // wave-uniform skip: chunk min j beyond this wave's rows
        {
            int jmin = band ? jbase : jof(cc * 64, r0, r1, r2);
            if (jmin > iw0 + 15) continue;
        }

        // S^T = K Q^T over 4 tiles of 16 keys (swapped operands)
        f32x4 S[4];
#pragma unroll
        for (int tn = 0; tn < 4; tn++) S[tn] = (f32x4){0.f, 0.f, 0.f, 0.f};
#pragma unroll
        for (int f = 0; f < 4; f++) {
            bf16x8 kf[4];
#pragma unroll
            for (int tn = 0; tn < 4; tn++)
                kf[tn] = *(const bf16x8*)&Ks[(tn * 16 + lr) * LSK + f * 32 + quad * 8];
#pragma unroll
            for (int tn = 0; tn < 4; tn++)
                S[tn] = __builtin_amdgcn_mfma_f32_16x16x32_bf16(kf[tn], qf[f], S[tn], 0, 0, 0);
        }

        // mask: lane holds S[q=iq][key = tn*16 + quad*4 + r].
        // Fast path (wave-uniform): interior fano chunk — every key <=
        // every row of this wave, keys are line-members by construction.
        const bool interior = !band && (jof(cc * 64 + 63, r0, r1, r2) <= iw0);
        if (interior) {
#pragma unroll
            for (int tn = 0; tn < 4; tn++)
#pragma unroll
                for (int r = 0; r < 4; r++) S[tn][r] *= scale;
        } else if (band) {
            // band: 0<=j<=i, j>=i-16, j%7 not in line (disjoint from fano)
#pragma unroll
            for (int tn = 0; tn < 4; tn++)
#pragma unroll
                for (int r = 0; r < 4; r++) {
                    int j = jbase + tn * 16 + quad * 4 + r;
                    int jm = ((j % 7) + 7) % 7;
                    bool ok = (j >= 0) && !((lm >> jm) & 1) &&
                              (j <= iq) && (j >= iq - 16);
                    S[tn][r] = ok ? S[tn][r] * scale : -1e30f;
                }
        } else {
            // straddling fano chunk: causal mask only
#pragma unroll
            for (int tn = 0; tn < 4; tn++) {
                int p0 = cc * 64 + tn * 16 + quad * 4;
                int g = p0 / 3, rs = p0 - 3 * g;
#pragma unroll
                for (int r = 0; r < 4; r++) {
                    int j = 7 * g + ((rs == 0) ? r0 : (rs == 1) ? r1 : r2);
                    S[tn][r] = (j <= iq) ? S[tn][r] * scale : -1e30f;
                    if (++rs == 3) { rs = 0; ++g; }
                }
            }
        }

        // online softmax: row = lr (lane-local 16 values + cross-quad reduce)
        float cm = -1e30f;
#pragma unroll
        for (int tn = 0; tn < 4; tn++)
#pragma unroll
            for (int r = 0; r < 4; r++) cm = fmaxf(cm, S[tn][r]);
        cm = fmaxf(cm, __shfl_xor(cm, 16));
        cm = fmaxf(cm, __shfl_xor(cm, 32));

        // T13 defer-max, THR=8: skip rescale when max growth <= 8 for all
        // rows in the wave; P bounded by e^8, bf16/f32-safe. The m >= -60
        // guard keeps all-masked rows on the exact path.
        const bool defer = __all(cm <= m + 8.f && m >= -60.f);
        float mn, a = 1.f;
        if (defer) {
            mn = m;
        } else {
            mn = fmaxf(fmaxf(m, cm), -60.f);   // all-masked -> exact 0
            a = __expf(m - mn);
            m = mn;
        }
        float pr[4][4];
        float rs_ = 0.f;
#pragma unroll
        for (int tn = 0; tn < 4; tn++)
#pragma unroll
            for (int r = 0; r < 4; r++) {
                pr[tn][r] = __expf(S[tn][r] - mn);
                rs_ += pr[tn][r];
            }
        rs_ += __shfl_xor(rs_, 16);
        rs_ += __shfl_xor(rs_, 32);
        if (defer) {
            l = l + rs_;
        } else {
            l = l * a + rs_;
            // O-rescale: O rows are quad*4+r; row's a from lane (quad*4+r)
            float a4[4];
#pragma unroll
            for (int r = 0; r < 4; r++) a4[r] = __shfl(a, quad * 4 + r);
#pragma unroll
            for (int dt = 0; dt < 8; dt++)
#pragma unroll
                for (int r = 0; r < 4; r++) O[dt][r] *= a4[r];
        }

        // P -> PV A-frag, in-register (16 shfl + 8 selects; no LDS).
        // lane (lr,quad) holds P[lr][tn*16+quad*4+r]; target needs
        // P[lr][quad*8..+7] (pf0) and P[lr][32+quad*8..+7] (pf1), which live
        // in lanes srcA=32*(quad&1)+lr (r=0..3) and srcB=srcA+16 (r=0..3).
        unsigned u01[4], u23[4];
#pragma unroll
        for (int tn = 0; tn < 4; tn++) {
            u01[tn] = pk_bf2(pr[tn][0], pr[tn][1]);
            u23[tn] = pk_bf2(pr[tn][2], pr[tn][3]);
        }
        const int srcA = 32 * (quad & 1) + lr;
        const int srcB = srcA + 16;
        const bool hi = (quad >= 2);
        uint4 t0, t1;
        {
            unsigned d0a = __shfl(u01[0], srcA), d0b = __shfl(u01[1], srcA);
            unsigned d1a = __shfl(u23[0], srcA), d1b = __shfl(u23[1], srcA);
            unsigned d2a = __shfl(u01[0], srcB), d2b = __shfl(u01[1], srcB);
            unsigned d3a = __shfl(u23[0], srcB), d3b = __shfl(u23[1], srcB);
            t0.x = hi ? d0b : d0a;
            t0.y = hi ? d1b : d1a;
            t0.z = hi ? d2b : d2a;
            t0.w = hi ? d3b : d3a;
        }
        {
            unsigned d0a = __shfl(u01[2], srcA), d0b = __shfl(u01[3], srcA);
            unsigned d1a = __shfl(u23[2], srcA), d1b = __shfl(u23[3], srcA);
            unsigned d2a = __shfl(u01[2], srcB), d2b = __shfl(u01[3], srcB);
            unsigned d3a = __shfl(u23[2], srcB), d3b = __shfl(u23[3], srcB);
            t1.x = hi ? d0b : d0a;
            t1.y = hi ? d1b : d1a;
            t1.z = hi ? d2b : d2a;
            t1.w = hi ? d3b : d3a;
        }
        bf16x8 pf0 = *(const bf16x8*)&t0;
        bf16x8 pf1 = *(const bf16x8*)&t1;

#pragma unroll
        for (int dt = 0; dt < 8; dt++) {
            bf16x8 v0 = *(const bf16x8*)&Vt[(dt * 16 + lr) * LSV + quad * 8];
            bf16x8 v1 = *(const bf16x8*)&Vt[(dt * 16 + lr) * LSV + 32 + quad * 8];
            O[dt] = __builtin_amdgcn_mfma_f32_16x16x32_bf16(pf0, v0, O[dt], 0, 0, 0);
            O[dt] = __builtin_amdgcn_mfma_f32_16x16x32_bf16(pf1, v1, O[dt], 0, 0, 0);
        }
    }

    // write unnormalized partials (64 local rows per flat block id p)
    const size_t pbase = ((size_t)p * 7 + h) * 64;
#pragma unroll
    for (int dt = 0; dt < 8; dt++)
#pragma unroll
        for (int r = 0; r < 4; r++) {
            int lrow = w * 16 + quad * 4 + r;
            Opart[(pbase + lrow) * 128 + dt * 16 + lr] = bf1(O[dt][r]);
        }
    if (quad == 0) {   // softmax state lives at row = lr
        int lrow = w * 16 + lr;
        Lm[(pbase + lrow) * 2 + 0] = m;
        Lm[(pbase + lrow) * 2 + 1] = l;
    }
}

// ---------------------------------------------------------------------------
// Merge variable-count partials -> Ab (bf16). Grid (64,7), block 256.
// Thread = (local row = t>>2, 32-dim slice = (t&3)*32). Tile tt reads splits
// p in [P[tt], P[tt]+S(tt)), S <= MAXSPLIT; unroll-8 with guards keeps all
// array indexing static (no scratch).
// ---------------------------------------------------------------------------
__global__ __launch_bounds__(256)
void attn_merge(const ushort_t* __restrict__ Opart,
                const float* __restrict__ Lm,
                ushort_t* __restrict__ Ab) {
    const int h = blockIdx.y;
    const int tt = blockIdx.x;
    int pb = 0;
    for (int u = 0; u < tt; ++u) pb += nsplit_of(u);
    const int S = nsplit_of(tt);          // 1..8
    const int lrow = threadIdx.x >> 2;
    const int row = tt * 64 + lrow;
    const int d0 = (threadIdx.x & 3) * 32;

    float ms[MAXSPLIT], ls[MAXSPLIT], M = -1e30f;
#pragma unroll
    for (int s = 0; s < MAXSPLIT; s++) {
        ms[s] = -1e30f;
        ls[s] = 0.f;
        if (s < S) {
            size_t q = (((size_t)(pb + s) * 7 + h) * 64 + lrow) * 2;
            ms[s] = Lm[q];
            ls[s] = Lm[q + 1];
        }
        M = fmaxf(M, ms[s]);
    }
    float L = 0.f, c[MAXSPLIT];
#pragma unroll
    for (int s = 0; s < MAXSPLIT; s++) {
        c[s] = __expf(ms[s] - M);   // s>=S: exp(-1e30-M) == 0
        L += c[s] * ls[s];
    }
    float acc[32];
#pragma unroll
    for (int k = 0; k < 32; k++) acc[k] = 0.f;
#pragma unroll
    for (int s = 0; s < MAXSPLIT; s++) {
        if (s < S) {
            const float cs = c[s];
            const ushort_t* op =
                Opart + (((size_t)(pb + s) * 7 + h) * 64 + lrow) * 128 + d0;
#pragma unroll
            for (int v = 0; v < 4; v++) {
                uint4 u = *(const uint4*)(op + v * 8);
                acc[v * 8 + 0] += cs * lo_f(u.x);
                acc[v * 8 + 1] += cs * hi_f(u.x);
                acc[v * 8 + 2] += cs * lo_f(u.y);
                acc[v * 8 + 3] += cs * hi_f(u.y);
                acc[v * 8 + 4] += cs * lo_f(u.z);
                acc[v * 8 + 5] += cs * hi_f(u.z);
                acc[v * 8 + 6] += cs * lo_f(u.w);
                acc[v * 8 + 7] += cs * hi_f(u.w);
            }
        }
    }
    float invL = 1.f / L;   // L > 0: j==i lies in some split
    ushort_t* dst = Ab + (size_t)row * D_MODEL + h * 128 + d0;
#pragma unroll
    for (int v = 0; v < 4; v++) {
        uint4 u;
        u.x = f2bf(acc[v * 8 + 0] * invL) | (f2bf(acc[v * 8 + 1] * invL) << 16);
        u.y = f2bf(acc[v * 8 + 2] * invL) | (f2bf(acc[v * 8 + 3] * invL) << 16);
        u.z = f2bf(acc[v * 8 + 4] * invL) | (f2bf(acc[v * 8 + 5] * invL) << 16);
        u.w = f2bf(acc[v * 8 + 6] * invL) | (f2bf(acc[v * 8 + 7] * invL) << 16);
        *(uint4*)(dst + v * 8) = u;
    }
}

extern "C" void kernel_launch(void* const* d_in, const int* in_sizes, int n_in,
                              void* d_out, int out_size, void* d_ws, size_t ws_size,
                              hipStream_t stream) {
    const float* x  = (const float*)d_in[0];   // fp32 [4096, 896]
    const float* Wq = (const float*)d_in[1];   // fp32 [896, 896]
    const float* Wk = (const float*)d_in[2];
    const float* Wv = (const float*)d_in[3];
    const float* Wo = (const float*)d_in[4];

    // total attention blocks in the balanced schedule
    int NP = 0;
    for (int u = 0; u < 64; ++u) NP += nsplit_of(u);

    const size_t n  = (size_t)T_SEQ * D_MODEL;
    const size_t nw = (size_t)D_MODEL * D_MODEL;
    ushort_t* xb  = (ushort_t*)d_ws + 128;   // 256B offset
    ushort_t* Wqb = xb + n;
    ushort_t* Wkb = Wqb + nw;
    ushort_t* Wvb = Wkb + nw;
    ushort_t* Wob = Wvb + nw;
    ushort_t* Qb  = Wob + nw;
    ushort_t* Kb  = Qb + n;
    ushort_t* Vb  = Kb + n;
    ushort_t* Ab  = Vb + n;
    ushort_t* Opart = Ab + n;                          // NP*7*64*128 bf16
    float*    Lm  = (float*)(Opart + (size_t)NP * 7 * 64 * 128);

    // 0: fp32 -> bf16 bulk convert (x + 4 weights)
    cvt5<<<dim3(1792, 5), 256, 0, stream>>>(x, Wq, Wk, Wv, Wo,
                                            xb, Wqb, Wkb, Wvb, Wob);
    // 1: Q/K/V = x @ W^T (bf16, DMA-staged)
    gemm_nt_dma<false><<<dim3(32, 7, 3), 256, 0, stream>>>(
        xb, Wqb, Wkb, Wvb, Qb, Kb, Vb);
    // 2: balanced split-K sparse attention -> partials
    fano_attn_split<<<dim3(NP, 7), 256, 0, stream>>>(
        Qb, Kb, Vb, Opart, Lm);
    // 3: merge partials -> Ab
    attn_merge<<<dim3(64, 7), 256, 0, stream>>>(Opart, Lm, Ab);
    // 4: out = Ab @ Wo^T -> fp32
    gemm_nt_dma<true><<<dim3(32, 7, 1), 256, 0, stream>>>(
        Ab, Wob, Wob, Wob, d_out, d_out, d_out);
}